// Round 2
// baseline (280.659 us; speedup 1.0000x reference)
//
#include <hip/hip_runtime.h>
#include <hip/hip_bf16.h>

// GIN layer: out = relu(((1+eps)*x + segment_sum(x[src], dst)) @ W1 + b1) @ W2 + b2
// Restructured via linearity: y = x@W1 (bf16); h = relu((1+eps)*y[i] + sum_j y[j] + b1);
// out = h@W2 + b2.
// CSR build: LDS-histogram counting sort (round-0 scheme; global atomics measured 6x slower).
// Gather: 4 column passes of 32 cols so each 3.2MB slice of y is per-XCD-L2 resident.
// N=50000 nodes, E=1.6M edges, D=128.

#define N_NODES 50000
#define N_EDGES 1600000
#define D 128

#define NB_H 256                 // private histograms (one owner block each)
#define CHUNK (N_EDGES / NB_H)   // 6250 edges per chunk; rank max 6249 < 65536
#define HROW 50016               // ushorts per hist row (100,032 B, 128-aligned)

#define GP_BLOCKS 12500          // gather blocks per column pass (4 nodes/block)

typedef __attribute__((ext_vector_type(8))) short short8;
typedef __attribute__((ext_vector_type(4))) float float4v;

__device__ inline unsigned short f2b(float f) {
    unsigned u = __builtin_bit_cast(unsigned, f);
    u = u + 0x7fffu + ((u >> 16) & 1u);  // RNE
    return (unsigned short)(u >> 16);
}
__device__ inline float b2f_lo(unsigned u) { return __builtin_bit_cast(float, u << 16); }
__device__ inline float b2f_hi(unsigned u) { return __builtin_bit_cast(float, u & 0xffff0000u); }

#define LPAD 136

// ---------------- y = bf16(x @ W1)  (f32 A staged+converted in LDS; no bias/relu) ------
// Also: block 0 detects int64-vs-int32 edge layout.
__global__ __launch_bounds__(256, 2) void k_gemmY(const float* __restrict__ x,
                                                  const float* __restrict__ Wg,
                                                  unsigned short* __restrict__ y,
                                                  const int* __restrict__ ei,
                                                  int* __restrict__ flag) {
    if (blockIdx.x == 0) {
        __shared__ int nz;
        if (threadIdx.x == 0) nz = 0;
        __syncthreads();
        if (ei[threadIdx.x * 2 + 1] != 0) atomicAdd(&nz, 1);
        __syncthreads();
        if (threadIdx.x == 0) *flag = (nz == 0) ? 1 : 0;  // 1 => int64 layout
    }

    __shared__ short Al[128 * LPAD];   // [row][k] bf16
    __shared__ short Wt[128 * LPAD];   // [n][k]   bf16 (transposed W)
    int t = threadIdx.x;
    int row0 = blockIdx.x * 128;

    const float4* X4 = (const float4*)x;
    #pragma unroll
    for (int i = 0; i < 16; ++i) {
        int idx = i * 256 + t;      // 0..4095
        int r = idx >> 5;           // 0..127
        int c = idx & 31;           // float4 within row
        float4 v = make_float4(0.f, 0.f, 0.f, 0.f);
        if (row0 + r < N_NODES) v = X4[(size_t)(row0 + r) * 32 + c];
        short4 o;
        o.x = (short)f2b(v.x); o.y = (short)f2b(v.y);
        o.z = (short)f2b(v.z); o.w = (short)f2b(v.w);
        *(short4*)&Al[r * LPAD + c * 4] = o;
    }
    const float4* W4 = (const float4*)Wg;
    #pragma unroll
    for (int i = 0; i < 16; ++i) {
        int idx = i * 256 + t;
        int k = idx >> 5;
        int n4 = idx & 31;
        float4 v = W4[k * 32 + n4];
        Wt[(n4 * 4 + 0) * LPAD + k] = (short)f2b(v.x);
        Wt[(n4 * 4 + 1) * LPAD + k] = (short)f2b(v.y);
        Wt[(n4 * 4 + 2) * LPAD + k] = (short)f2b(v.z);
        Wt[(n4 * 4 + 3) * LPAD + k] = (short)f2b(v.w);
    }
    __syncthreads();

    int wave = t >> 6;
    int lane = t & 63;
    int quad = lane >> 4;
    int l16 = lane & 15;
    int rowbase = wave * 32;

    float4v acc[2][8];
    #pragma unroll
    for (int mt = 0; mt < 2; ++mt)
        #pragma unroll
        for (int nt = 0; nt < 8; ++nt)
            acc[mt][nt] = (float4v){0.f, 0.f, 0.f, 0.f};

    #pragma unroll
    for (int kc = 0; kc < 4; ++kc) {
        int koff = kc * 32 + quad * 8;
        short8 a0 = *(const short8*)&Al[(rowbase + l16) * LPAD + koff];
        short8 a1 = *(const short8*)&Al[(rowbase + 16 + l16) * LPAD + koff];
        #pragma unroll
        for (int nt = 0; nt < 8; ++nt) {
            short8 bfr = *(const short8*)&Wt[(nt * 16 + l16) * LPAD + koff];
            acc[0][nt] = __builtin_amdgcn_mfma_f32_16x16x32_bf16(a0, bfr, acc[0][nt], 0, 0, 0);
            acc[1][nt] = __builtin_amdgcn_mfma_f32_16x16x32_bf16(a1, bfr, acc[1][nt], 0, 0, 0);
        }
    }

    #pragma unroll
    for (int mt = 0; mt < 2; ++mt) {
        int rloc = rowbase + mt * 16 + quad * 4;
        #pragma unroll
        for (int nt = 0; nt < 8; ++nt) {
            int col = nt * 16 + l16;
            #pragma unroll
            for (int r = 0; r < 4; ++r) {
                int grow = row0 + rloc + r;
                if (grow < N_NODES)
                    y[(size_t)grow * 128 + col] = f2b(acc[mt][nt][r]);
            }
        }
    }
}

// ---------------- LDS histogram (packed u16 pairs) + per-edge rank ----------------
__global__ __launch_bounds__(1024) void k_hist_rank(const int* __restrict__ ei,
                                                    const int* __restrict__ flag,
                                                    unsigned* __restrict__ cntw,
                                                    int* __restrict__ rank) {
    __shared__ unsigned hist[HROW / 2];  // 25008 u32 = 100,032 B
    int b = blockIdx.x;
    for (int i = threadIdx.x; i < HROW / 2; i += 1024) hist[i] = 0u;
    __syncthreads();
    int wide = *flag;
    int e0 = b * CHUNK;
    for (int i = threadIdx.x; i < CHUNK; i += 1024) {
        int e = e0 + i;
        long long di = (long long)N_EDGES + e;
        int d = wide ? ei[di * 2] : ei[di];
        int r = 0;
        if ((unsigned)d < (unsigned)N_NODES) {
            int sh = (d & 1) * 16;
            unsigned old = atomicAdd(&hist[d >> 1], 1u << sh);
            r = (old >> sh) & 0xffffu;
        }
        rank[e] = r;  // coalesced
    }
    __syncthreads();
    unsigned* row = cntw + (size_t)b * (HROW / 2);
    for (int i = threadIdx.x; i < HROW / 2; i += 1024) row[i] = hist[i];
}

// ---------------- fused column scan + per-block scan of deg ----------------
// cnt16[b][d] -> exclusive prefix over b; deg[d] = total; offsets[d] = within-block
// exclusive prefix of deg; bsum[block] = block total.
__global__ __launch_bounds__(512) void k_colscan_scan1(unsigned short* __restrict__ cnt16,
                                                       int* __restrict__ deg,
                                                       int* __restrict__ offsets,
                                                       int* __restrict__ bsum) {
    __shared__ int tmp[512];
    int t = threadIdx.x;
    int d = blockIdx.x * 512 + t;
    int run = 0;
    if (d < N_NODES) {
        #pragma unroll 8
        for (int b = 0; b < NB_H; ++b) {
            size_t idx = (size_t)b * HROW + d;
            int v = cnt16[idx];
            cnt16[idx] = (unsigned short)run;
            run += v;
        }
        deg[d] = run;
    }
    tmp[t] = run;
    __syncthreads();
    for (int off = 1; off < 512; off <<= 1) {
        int u = (t >= off) ? tmp[t - off] : 0;
        __syncthreads();
        tmp[t] += u;
        __syncthreads();
    }
    if (d < N_NODES) offsets[d] = tmp[t] - run;
    if (t == 511) bsum[blockIdx.x] = tmp[511];
}

// ---------------- fused scan of block sums + add base ----------------
__global__ __launch_bounds__(512) void k_scan23(int* __restrict__ offsets,
                                                const int* __restrict__ bsum, int nb) {
    __shared__ int tmp[128];
    int t = threadIdx.x;
    if (t < 128) tmp[t] = (t < nb) ? bsum[t] : 0;
    __syncthreads();
    for (int off = 1; off < 128; off <<= 1) {
        int v = (t >= off && t < 128) ? tmp[t - off] : 0;
        __syncthreads();
        if (t < 128) tmp[t] += v;
        __syncthreads();
    }
    int base = (blockIdx.x == 0) ? 0 : tmp[blockIdx.x - 1];
    int gid = blockIdx.x * 512 + t;
    if (gid < N_NODES) offsets[gid] += base;
}

// ---------------- CSR place (no atomics, one edge per thread) ----------------
__global__ __launch_bounds__(1024) void k_place(const int* __restrict__ ei,
                                                const int* __restrict__ flag,
                                                const int* __restrict__ offsets,
                                                const unsigned short* __restrict__ cnt16,
                                                const int* __restrict__ rank,
                                                int* __restrict__ srcs) {
    int e = blockIdx.x * 1024 + threadIdx.x;
    if (e >= N_EDGES) return;
    int wide = *flag;
    int s = wide ? ei[(long long)e * 2] : ei[e];
    long long di = (long long)N_EDGES + e;
    int d = wide ? ei[di * 2] : ei[di];
    if ((unsigned)d < (unsigned)N_NODES && (unsigned)s < (unsigned)N_NODES) {
        int b = e / CHUNK;
        srcs[offsets[d] + cnt16[(size_t)b * HROW + d] + rank[e]] = s;
    }
}

// ---------------- gather over y, 4 column passes, fused layer-1 epilogue --------------
// h[i] = bf16(relu((1+eps)*y[i] + sum_{j in N(i)} y[j] + b1))
// pass p covers cols [32p, 32p+32) = 64 B/row -> 3.2 MB slice, per-XCD-L2 resident.
// Wave = 1 node: 8 lanes per row (uint2 each), 8 neighbors in flight, x2 unroll.
__global__ __launch_bounds__(256) void k_gather(const unsigned short* __restrict__ y,
                                                const int* __restrict__ srcs,
                                                const int* __restrict__ offsets,
                                                const int* __restrict__ deg,
                                                const float* __restrict__ b1,
                                                unsigned short* __restrict__ h) {
    int pass = blockIdx.x / GP_BLOCKS;          // 0..3 (blocks launch ~in order)
    int nb   = blockIdx.x % GP_BLOCKS;
    int node = nb * 4 + (threadIdx.x >> 6);     // < 50000 always (12500*4)
    int lane = threadIdx.x & 63;
    int n = lane >> 3;       // neighbor slot 0..7
    int u = lane & 7;        // uint2 within the 64B slice
    int cu = pass * 8 + u;   // uint2 index within the 256B row

    int beg = offsets[node];
    int end = beg + deg[node];
    const uint2* yr = (const uint2*)y;
    float a0 = 0.f, a1 = 0.f, a2 = 0.f, a3 = 0.f;

    int j = beg + n;
    for (; j + 8 < end; j += 16) {
        int s0 = srcs[j];
        int s1 = srcs[j + 8];
        uint2 A0 = yr[(size_t)s0 * 32 + cu];
        uint2 A1 = yr[(size_t)s1 * 32 + cu];
        a0 += b2f_lo(A0.x); a1 += b2f_hi(A0.x);
        a2 += b2f_lo(A0.y); a3 += b2f_hi(A0.y);
        a0 += b2f_lo(A1.x); a1 += b2f_hi(A1.x);
        a2 += b2f_lo(A1.y); a3 += b2f_hi(A1.y);
    }
    for (; j < end; j += 8) {
        int s = srcs[j];
        uint2 A = yr[(size_t)s * 32 + cu];
        a0 += b2f_lo(A.x); a1 += b2f_hi(A.x);
        a2 += b2f_lo(A.y); a3 += b2f_hi(A.y);
    }
    // reduce over the 8 neighbor slots (lanes differing in bits 3..5)
    a0 += __shfl_xor(a0, 8, 64); a1 += __shfl_xor(a1, 8, 64);
    a2 += __shfl_xor(a2, 8, 64); a3 += __shfl_xor(a3, 8, 64);
    a0 += __shfl_xor(a0, 16, 64); a1 += __shfl_xor(a1, 16, 64);
    a2 += __shfl_xor(a2, 16, 64); a3 += __shfl_xor(a3, 16, 64);
    a0 += __shfl_xor(a0, 32, 64); a1 += __shfl_xor(a1, 32, 64);
    a2 += __shfl_xor(a2, 32, 64); a3 += __shfl_xor(a3, 32, 64);

    if (n == 0) {
        uint2 S = yr[(size_t)node * 32 + cu];   // self row slice (bf16 y)
        float4 bv = ((const float4*)b1)[cu];    // bias cols 4cu..4cu+3
        float f0 = fmaf(1.001f, b2f_lo(S.x), a0) + bv.x;
        float f1 = fmaf(1.001f, b2f_hi(S.x), a1) + bv.y;
        float f2 = fmaf(1.001f, b2f_lo(S.y), a2) + bv.z;
        float f3 = fmaf(1.001f, b2f_hi(S.y), a3) + bv.w;
        f0 = fmaxf(f0, 0.f); f1 = fmaxf(f1, 0.f);
        f2 = fmaxf(f2, 0.f); f3 = fmaxf(f3, 0.f);
        uint2 o;
        o.x = (unsigned)f2b(f0) | ((unsigned)f2b(f1) << 16);
        o.y = (unsigned)f2b(f2) | ((unsigned)f2b(f3) << 16);
        ((uint2*)h)[(size_t)node * 32 + cu] = o;
    }
}

// ---------------- bf16 MFMA GEMM: out[M,128] = A_bf16[M,128] @ W[128,128] + b ---------
template <int RELU, int OUT_BF16>
__global__ __launch_bounds__(256, 2) void k_gemm(const unsigned short* __restrict__ A,
                                                 const float* __restrict__ Wg,
                                                 const float* __restrict__ bias,
                                                 void* __restrict__ outv, int M) {
    __shared__ short Al[128 * LPAD];   // [row][k]
    __shared__ short Wt[128 * LPAD];   // [n][k]  (transposed W)
    __shared__ float bl[128];

    int t = threadIdx.x;
    int row0 = blockIdx.x * 128;

    const uint4* A16 = (const uint4*)A;
    #pragma unroll
    for (int i = 0; i < 8; ++i) {
        int idx = i * 256 + t;      // 0..2047
        int r = idx >> 4;           // 0..127
        int c = idx & 15;           // uint4 within row
        uint4 v = make_uint4(0u, 0u, 0u, 0u);
        if (row0 + r < M) v = A16[(size_t)(row0 + r) * 16 + c];
        *(uint4*)&Al[r * LPAD + c * 8] = v;
    }
    const float4* W4 = (const float4*)Wg;
    #pragma unroll
    for (int i = 0; i < 16; ++i) {
        int idx = i * 256 + t;
        int k = idx >> 5;
        int n4 = idx & 31;
        float4 v = W4[k * 32 + n4];
        Wt[(n4 * 4 + 0) * LPAD + k] = (short)f2b(v.x);
        Wt[(n4 * 4 + 1) * LPAD + k] = (short)f2b(v.y);
        Wt[(n4 * 4 + 2) * LPAD + k] = (short)f2b(v.z);
        Wt[(n4 * 4 + 3) * LPAD + k] = (short)f2b(v.w);
    }
    if (t < 32) ((float4*)bl)[t] = ((const float4*)bias)[t];
    __syncthreads();

    int wave = t >> 6;
    int lane = t & 63;
    int quad = lane >> 4;
    int l16 = lane & 15;
    int rowbase = wave * 32;

    float4v acc[2][8];
    #pragma unroll
    for (int mt = 0; mt < 2; ++mt)
        #pragma unroll
        for (int nt = 0; nt < 8; ++nt)
            acc[mt][nt] = (float4v){0.f, 0.f, 0.f, 0.f};

    #pragma unroll
    for (int kc = 0; kc < 4; ++kc) {
        int koff = kc * 32 + quad * 8;
        short8 a0 = *(const short8*)&Al[(rowbase + l16) * LPAD + koff];
        short8 a1 = *(const short8*)&Al[(rowbase + 16 + l16) * LPAD + koff];
        #pragma unroll
        for (int nt = 0; nt < 8; ++nt) {
            short8 bfr = *(const short8*)&Wt[(nt * 16 + l16) * LPAD + koff];
            acc[0][nt] = __builtin_amdgcn_mfma_f32_16x16x32_bf16(a0, bfr, acc[0][nt], 0, 0, 0);
            acc[1][nt] = __builtin_amdgcn_mfma_f32_16x16x32_bf16(a1, bfr, acc[1][nt], 0, 0, 0);
        }
    }

    #pragma unroll
    for (int mt = 0; mt < 2; ++mt) {
        int rloc = rowbase + mt * 16 + quad * 4;
        #pragma unroll
        for (int nt = 0; nt < 8; ++nt) {
            int col = nt * 16 + l16;
            float bv = bl[col];
            #pragma unroll
            for (int r = 0; r < 4; ++r) {
                int grow = row0 + rloc + r;
                if (grow < M) {
                    float v = acc[mt][nt][r] + bv;
                    if (RELU) v = fmaxf(v, 0.f);
                    if (OUT_BF16)
                        ((unsigned short*)outv)[(size_t)grow * 128 + col] = f2b(v);
                    else
                        ((float*)outv)[(size_t)grow * 128 + col] = v;
                }
            }
        }
    }
}

extern "C" void kernel_launch(void* const* d_in, const int* in_sizes, int n_in,
                              void* d_out, int out_size, void* d_ws, size_t ws_size,
                              hipStream_t stream) {
    const float* x  = (const float*)d_in[0];
    const int*   ei = (const int*)d_in[1];
    const float* W1 = (const float*)d_in[2];
    const float* b1 = (const float*)d_in[3];
    const float* W2 = (const float*)d_in[4];
    const float* b2 = (const float*)d_in[5];
    float* out = (float*)d_out;

    // workspace layout (bytes):
    //   [0,        12.8e6)   y bf16 (x @ W1) — live gemmY .. gather
    //   [12.8e6,   38.41e6)  cnt u16 matrix (256 x 50016 x 2B) — dead after place
    //   [12.8e6,   25.6e6)   h bf16 — aliases cnt, written by gather (after place)
    //   [38.5e6,   44.9e6)   rank — dead after place
    //   [44.9e6,   51.3e6)   srcs
    //   [51.4e6, ...)        deg, offsets, bsum, flag
    char* ws = (char*)d_ws;
    unsigned short* y       = (unsigned short*)(ws);
    unsigned*       cntw    = (unsigned*)(ws + 12800000);
    unsigned short* cnt16   = (unsigned short*)(ws + 12800000);
    unsigned short* hb      = (unsigned short*)(ws + 12800000);
    int*            rank    = (int*)  (ws + 38500000);
    int*            srcs    = (int*)  (ws + 44900000);
    int*            deg     = (int*)  (ws + 51400000);
    int*            offsets = (int*)  (ws + 51600000);
    int*            bsum    = (int*)  (ws + 51800000);
    int*            flag    = (int*)  (ws + 51810000);

    const int NB_SCAN = (N_NODES + 511) / 512;  // 98
    int gblocks = (N_NODES + 127) / 128;        // 391

    k_gemmY<<<gblocks, 256, 0, stream>>>(x, W1, y, ei, flag);
    k_hist_rank<<<NB_H, 1024, 0, stream>>>(ei, flag, cntw, rank);
    k_colscan_scan1<<<NB_SCAN, 512, 0, stream>>>(cnt16, deg, offsets, bsum);
    k_scan23<<<NB_SCAN, 512, 0, stream>>>(offsets, bsum, NB_SCAN);
    k_place<<<(N_EDGES + 1023) / 1024, 1024, 0, stream>>>(ei, flag, offsets, cnt16, rank, srcs);
    k_gather<<<4 * GP_BLOCKS, 256, 0, stream>>>(y, srcs, offsets, deg, b1, hb);
    k_gemm<0, 0><<<gblocks, 256, 0, stream>>>(hb, W2, b2, out, N_NODES);
}